// Round 5
// baseline (234.468 us; speedup 1.0000x reference)
//
#include <hip/hip_runtime.h>
#include <hip/hip_bf16.h>
#include <stdint.h>

// Problem constants
#define B_   4
#define S_   2048
#define E_   1024
#define H_   16
#define D_   64
#define M_   (B_ * S_)     // 8192 rows
#define E3_  (3 * E_)      // 3072

#define QSCALE 0.18033688011112042f  // 0.125 * log2(e)

typedef __bf16 bf16_t;
typedef bf16_t bf16x8 __attribute__((ext_vector_type(8)));
typedef float  f32x4  __attribute__((ext_vector_type(4)));
typedef float  f32x16 __attribute__((ext_vector_type(16)));

__device__ __forceinline__ ushort f2bf(float f) {
  union { float f; uint32_t u; } v; v.f = f;
  uint32_t r = v.u + 0x7fffu + ((v.u >> 16) & 1u);
  return (ushort)(r >> 16);
}

__device__ __forceinline__ unsigned cvtpk(float lo, float hi_) {
  unsigned d;
  asm("v_cvt_pk_bf16_f32 %0, %1, %2" : "=v"(d) : "v"(lo), "v"(hi_));
  return d;
}

__device__ __forceinline__ void gload_lds16(const void* g, void* l) {
  __builtin_amdgcn_global_load_lds((const __attribute__((address_space(1))) void*)g,
                                   (__attribute__((address_space(3))) void*)l,
                                   16, 0, 0);
}

// ---------------------------------------------------------------- cvt f32->bf16 (optional row-scale)
__global__ __launch_bounds__(256) void cvt_f32_bf16(const float* __restrict__ in,
                                                    ushort* __restrict__ out, int n4,
                                                    int scale_row4, float scale) {
  int i = blockIdx.x * blockDim.x + threadIdx.x;
  if (i < n4) {
    float4 v = reinterpret_cast<const float4*>(in)[i];
    if (i < scale_row4) { v.x *= scale; v.y *= scale; v.z *= scale; v.w *= scale; }
    ushort4 o;
    o.x = f2bf(v.x); o.y = f2bf(v.y); o.z = f2bf(v.z); o.w = f2bf(v.w);
    reinterpret_cast<ushort4*>(out)[i] = o;
  }
}

// ---------------------------------------------------------------- GEMM: C = A @ Bt^T + bias
// MODE 0: f32 out [Mdim][Ndim]. MODE 1: qkv split: cols<2048 -> bf16 qk[row][2048],
//         cols>=2048 -> vT[(b*1024 + col-2048)][2048] packed along s; q-bias scaled.
template <int MODE>
__global__ __launch_bounds__(256) void gemm_bt(const ushort* __restrict__ A,
                                               const ushort* __restrict__ Bt,
                                               const float* __restrict__ bias,
                                               void* __restrict__ out0,
                                               ushort* __restrict__ vTout,
                                               int Mdim, int Ndim, int K) {
  __shared__ __align__(16) ushort As[128 * 32];
  __shared__ __align__(16) ushort Bs[128 * 32];

  const int tid  = threadIdx.x;
  const int lane = tid & 63, wid = tid >> 6;
  const int wr = wid >> 1, wc = wid & 1;
  const int bm = blockIdx.y * 128, bn = blockIdx.x * 128;
  const int lrow = lane & 15, lk8 = (lane >> 4) * 8, lg4 = (lane >> 4) * 4;
  const int srow = tid >> 2;
  const int skk  = (tid & 3) * 8;

  f32x4 acc[4][4] = {};

  for (int k0 = 0; k0 < K; k0 += 32) {
#pragma unroll
    for (int j = 0; j < 2; ++j) {
      const ushort* ga = A  + (size_t)(bm + j * 64 + srow) * K + k0 + skk;
      const ushort* gb = Bt + (size_t)(bn + j * 64 + srow) * K + k0 + skk;
      gload_lds16(ga, (void*)&As[(j * 256 + wid * 64) * 8]);
      gload_lds16(gb, (void*)&Bs[(j * 256 + wid * 64) * 8]);
    }
    __syncthreads();

    bf16x8 af[4], bfv[4];
#pragma unroll
    for (int rb = 0; rb < 4; ++rb)
      af[rb] = *reinterpret_cast<const bf16x8*>(&As[(wr * 64 + rb * 16 + lrow) * 32 + lk8]);
#pragma unroll
    for (int cb = 0; cb < 4; ++cb)
      bfv[cb] = *reinterpret_cast<const bf16x8*>(&Bs[(wc * 64 + cb * 16 + lrow) * 32 + lk8]);
#pragma unroll
    for (int rb = 0; rb < 4; ++rb)
#pragma unroll
      for (int cb = 0; cb < 4; ++cb)
        acc[rb][cb] = __builtin_amdgcn_mfma_f32_16x16x32_bf16(af[rb], bfv[cb], acc[rb][cb], 0, 0, 0);
    __syncthreads();
  }

#pragma unroll
  for (int rb = 0; rb < 4; ++rb) {
#pragma unroll
    for (int cb = 0; cb < 4; ++cb) {
      const int col = bn + wc * 64 + cb * 16 + lrow;
      float bv = bias[col];
      if (MODE == 1 && col < 1024) bv *= QSCALE;
      const int row0 = bm + wr * 64 + rb * 16 + lg4;
      if (MODE == 0) {
#pragma unroll
        for (int r = 0; r < 4; ++r)
          ((float*)out0)[(size_t)(row0 + r) * Ndim + col] = acc[rb][cb][r] + bv;
      } else {
        if (col < 2048) {
#pragma unroll
          for (int r = 0; r < 4; ++r)
            ((ushort*)out0)[(size_t)(row0 + r) * 2048 + col] = f2bf(acc[rb][cb][r] + bv);
        } else {
          ushort4 vv;
          vv.x = f2bf(acc[rb][cb][0] + bv);
          vv.y = f2bf(acc[rb][cb][1] + bv);
          vv.z = f2bf(acc[rb][cb][2] + bv);
          vv.w = f2bf(acc[rb][cb][3] + bv);
          const size_t vidx = ((size_t)((row0 >> 11) * 1024 + (col - 2048))) * 2048 + (row0 & 2047);
          *reinterpret_cast<ushort4*>(&vTout[vidx]) = vv;
        }
      }
    }
  }
}

// ---------------------------------------------------------------- causal flash attention
// 4 waves x 32 q-rows = 128 q/block; 16 q-tiles x 64 bh = 1024 blocks (heavy tiles first).
// Swapped QK^T: lane owns q = lane&31, P lane-local. qk: [M_][2048] bf16 (q | k).
// vT: [bh*64+d][2048] bf16 (s-contiguous). ctx: [M_][E_] bf16.
__global__ __launch_bounds__(256) void attn_causal(const ushort* __restrict__ qk,
                                                   const ushort* __restrict__ vT,
                                                   ushort* __restrict__ ctx) {
  __shared__ __align__(16) char lds[2][16384];  // [buf][ K 8KB | Vt 8KB ], XOR-swizzled rows

  const int tid = threadIdx.x;
  const int w = tid >> 6, lane = tid & 63;
  const int l31 = lane & 31, hi = lane >> 5;

  const int bid = blockIdx.x;
  const int bh = bid & 63;            // bid%8 = bh%8 -> 8 heads' K/V per XCD L2
  const int qt = 15 - (bid >> 6);     // heavy q-tiles dispatched first
  const int b = bh >> 4, h = bh & 15;
  const int qbase = qt * 128;
  const int tmax = 2 * qt + 1;
  const int qw = qbase + w * 32;
  const int q_g = qw + l31;
  const int my_tmax = (qw + 31) >> 6;

  // Q fragments (scale pre-folded into W_in q-rows)
  const ushort* qrow = qk + (size_t)(b * S_ + q_g) * 2048 + h * 64;
  bf16x8 qf[4];
#pragma unroll
  for (int st = 0; st < 4; ++st)
    qf[st] = *reinterpret_cast<const bf16x8*>(qrow + st * 16 + hi * 8);

  // staging: 256 threads x 16B = 4KB per issue; 2 issues per 8KB tile, for K and Vt
  const int srow = tid >> 3;   // 0..31
  const int swz  = ((tid & 7) * 16) ^ ((srow & 7) << 4);
  const char* kbase = (const char*)qk + ((size_t)(b * S_ + srow) * 2048 + 1024 + h * 64) * 2 + swz;
  const char* vbase = (const char*)vT + ((size_t)(bh * 64 + srow) * 2048) * 2 + swz;

  f32x16 Ot0 = {}, Ot1 = {};
  float m_r = -__builtin_inff(), l_r = 0.f;

  const int kswz = ((l31 & 7) << 4);

#define STAGE(T, BUFI)                                                                     \
  do {                                                                                     \
    gload_lds16(kbase + ((size_t)(T) * 64 +  0) * 4096, &lds[BUFI][w * 1024]);             \
    gload_lds16(kbase + ((size_t)(T) * 64 + 32) * 4096, &lds[BUFI][4096 + w * 1024]);      \
    gload_lds16(vbase + (size_t)(T) * 128,              &lds[BUFI][8192 + w * 1024]);      \
    gload_lds16(vbase + (size_t)(T) * 128 + 32 * 4096,  &lds[BUFI][12288 + w * 1024]);     \
  } while (0)

  STAGE(0, 0);
  for (int t = 0; t <= tmax; ++t) {
    const int bufi = t & 1;
    if (t < tmax) {
      STAGE(t + 1, bufi ^ 1);
      asm volatile("s_waitcnt vmcnt(4)" ::: "memory");
    } else {
      asm volatile("s_waitcnt vmcnt(0)" ::: "memory");
    }
    __builtin_amdgcn_s_barrier();
    __builtin_amdgcn_sched_barrier(0);

    if (t <= my_tmax) {
      const char* Kt = &lds[bufi][0];
      const char* Vp = &lds[bufi][8192];

      // ---- S^T = K @ Q^T : lane owns column q = l31 ----
      f32x16 T0 = {}, T1 = {};
#pragma unroll
      for (int st = 0; st < 4; ++st) {
        const int cb = (st * 32 + hi * 16) ^ kswz;
        bf16x8 k0 = *(const bf16x8*)(Kt + l31 * 128 + cb);
        bf16x8 k1 = *(const bf16x8*)(Kt + (32 + l31) * 128 + cb);
        T0 = __builtin_amdgcn_mfma_f32_32x32x16_bf16(k0, qf[st], T0, 0, 0, 0);
        T1 = __builtin_amdgcn_mfma_f32_32x32x16_bf16(k1, qf[st], T1, 0, 0, 0);
      }

      // ---- mask + online softmax (lane-local, defer-max THR=8 in exp2 domain) ----
      float p[32];
      const bool needmask = (t * 64 + 63) > qw;
      const int kvb = t * 64 + 4 * hi;
#pragma unroll
      for (int g = 0; g < 4; ++g) {
#pragma unroll
        for (int j = 0; j < 4; ++j) {
          float v0 = T0[4 * g + j], v1 = T1[4 * g + j];
          if (needmask) {
            const int kv0 = kvb + 8 * g + j;
            v0 = (kv0      <= q_g) ? v0 : -__builtin_inff();
            v1 = (kv0 + 32 <= q_g) ? v1 : -__builtin_inff();
          }
          p[4 * g + j] = v0;
          p[16 + 4 * g + j] = v1;
        }
      }
      float pmax = p[0];
#pragma unroll
      for (int i = 1; i < 31; i += 2) pmax = fmaxf(fmaxf(pmax, p[i]), p[i + 1]);  // v_max3
      pmax = fmaxf(pmax, p[31]);
      pmax = fmaxf(pmax, __shfl_xor(pmax, 32));

      if (!__all(pmax - m_r <= 8.f)) {
        const float mn = fmaxf(m_r, pmax);
        const float sc = exp2f(m_r - mn);
        m_r = mn;
        l_r *= sc;
#pragma unroll
        for (int i = 0; i < 16; ++i) { Ot0[i] *= sc; Ot1[i] *= sc; }
      }
      float sum = 0.f;
#pragma unroll
      for (int i = 0; i < 32; ++i) { p[i] = exp2f(p[i] - m_r); sum += p[i]; }
      sum += __shfl_xor(sum, 32);
      l_r += sum;

      // ---- P -> bf16 B-fragments via shfl_xor(32) half-exchange; PV swapped: O^T col = q ----
#pragma unroll
      for (int ks = 0; ks < 4; ++ks) {
        const unsigned a = cvtpk(p[8 * ks + 0], p[8 * ks + 1]);
        const unsigned bq = cvtpk(p[8 * ks + 2], p[8 * ks + 3]);
        const unsigned c = cvtpk(p[8 * ks + 4], p[8 * ks + 5]);
        const unsigned d = cvtpk(p[8 * ks + 6], p[8 * ks + 7]);
        const unsigned x = hi ? a : c;
        const unsigned y = hi ? bq : d;
        const unsigned xp = (unsigned)__shfl_xor((int)x, 32);
        const unsigned yp = (unsigned)__shfl_xor((int)y, 32);
        union { unsigned u[4]; bf16x8 v; } pa;
        pa.u[0] = hi ? xp : a;   // k-elems 0,1
        pa.u[1] = hi ? yp : bq;  // k-elems 2,3
        pa.u[2] = hi ? c : xp;   // k-elems 4,5
        pa.u[3] = hi ? d : yp;   // k-elems 6,7
        const int cb = (ks * 32 + hi * 16) ^ kswz;
        bf16x8 v0 = *(const bf16x8*)(Vp + l31 * 128 + cb);
        bf16x8 v1 = *(const bf16x8*)(Vp + (32 + l31) * 128 + cb);
        Ot0 = __builtin_amdgcn_mfma_f32_32x32x16_bf16(v0, pa.v, Ot0, 0, 0, 0);
        Ot1 = __builtin_amdgcn_mfma_f32_32x32x16_bf16(v1, pa.v, Ot1, 0, 0, 0);
      }
    }
    __builtin_amdgcn_s_barrier();
    __builtin_amdgcn_sched_barrier(0);
  }

  // ---- epilogue: ctx[q][d] = O^T[d][q] / l ----
  const float inv = 1.0f / l_r;
  ushort* crow = ctx + (size_t)(b * S_ + q_g) * 1024 + h * 64;
#pragma unroll
  for (int g = 0; g < 4; ++g) {
#pragma unroll
    for (int jp = 0; jp < 2; ++jp) {
      const int d0 = 2 * jp + 8 * g + 4 * hi;
      const int r = 4 * g + 2 * jp;
      *(unsigned*)(crow + d0)      = cvtpk(Ot0[r] * inv, Ot0[r + 1] * inv);
      *(unsigned*)(crow + 32 + d0) = cvtpk(Ot1[r] * inv, Ot1[r + 1] * inv);
    }
  }
#undef STAGE
}

// ---------------------------------------------------------------- residual + LayerNorm
__global__ __launch_bounds__(256) void resid_ln(const float* __restrict__ x,
                                                const float* __restrict__ ao,
                                                const float* __restrict__ gamma,
                                                const float* __restrict__ beta,
                                                float* __restrict__ out) {
  const int row = blockIdx.x;
  const int tid = threadIdx.x;
  const size_t base = (size_t)row * E_;

  float4 xv = reinterpret_cast<const float4*>(x + base)[tid];
  float4 av = reinterpret_cast<const float4*>(ao + base)[tid];
  const float v0 = xv.x + av.x, v1 = xv.y + av.y, v2 = xv.z + av.z, v3 = xv.w + av.w;
  float s  = v0 + v1 + v2 + v3;
  float s2 = v0 * v0 + v1 * v1 + v2 * v2 + v3 * v3;
#pragma unroll
  for (int off = 32; off >= 1; off >>= 1) {
    s  += __shfl_xor(s, off);
    s2 += __shfl_xor(s2, off);
  }
  __shared__ float red[8];
  const int wid = tid >> 6, lane = tid & 63;
  if (lane == 0) { red[wid] = s; red[4 + wid] = s2; }
  __syncthreads();
  s  = red[0] + red[1] + red[2] + red[3];
  s2 = red[4] + red[5] + red[6] + red[7];
  const float mu  = s * (1.f / E_);
  const float var = s2 * (1.f / E_) - mu * mu;
  const float rsd = rsqrtf(var + 1e-5f);

  float4 gv = reinterpret_cast<const float4*>(gamma)[tid];
  float4 bv = reinterpret_cast<const float4*>(beta)[tid];
  float4 ov;
  ov.x = (v0 - mu) * rsd * gv.x + bv.x;
  ov.y = (v1 - mu) * rsd * gv.y + bv.y;
  ov.z = (v2 - mu) * rsd * gv.z + bv.z;
  ov.w = (v3 - mu) * rsd * gv.w + bv.w;
  reinterpret_cast<float4*>(out + base)[tid] = ov;
}

// ---------------------------------------------------------------- launch
extern "C" void kernel_launch(void* const* d_in, const int* in_sizes, int n_in,
                              void* d_out, int out_size, void* d_ws, size_t ws_size,
                              hipStream_t stream) {
  (void)in_sizes; (void)n_in; (void)out_size; (void)ws_size;
  const float* x     = (const float*)d_in[0];
  const float* w_in  = (const float*)d_in[1];
  const float* b_in  = (const float*)d_in[2];
  const float* w_out = (const float*)d_in[3];
  const float* b_out = (const float*)d_in[4];
  const float* gamma = (const float*)d_in[5];
  const float* beta  = (const float*)d_in[6];
  float* out = (float*)d_out;

  char* ws = (char*)d_ws;
  ushort* xb    = (ushort*)(ws);                          // 16 MB
  ushort* winb  = (ushort*)(ws + 16777216);               // 6 MB
  ushort* woutb = (ushort*)(ws + 23068672);               // 2 MB
  ushort* qkb   = (ushort*)(ws + 25165824);               // 32 MB  [8192][2048]
  ushort* vTb   = (ushort*)(ws + 58720256);               // 16 MB  [4096][2048]
  ushort* ctxb  = (ushort*)(ws + 75497472);               // 16 MB
  float*  ao    = (float*)(ws + 92274688);                // 32 MB  -> total 120 MB

  cvt_f32_bf16<<<dim3((M_ * E_) / 4 / 256), 256, 0, stream>>>(x, xb, (M_ * E_) / 4, 0, 1.f);
  cvt_f32_bf16<<<dim3((E3_ * E_) / 4 / 256), 256, 0, stream>>>(w_in, winb, (E3_ * E_) / 4,
                                                               (E_ * E_) / 4, QSCALE);
  cvt_f32_bf16<<<dim3((E_ * E_) / 4 / 256), 256, 0, stream>>>(w_out, woutb, (E_ * E_) / 4, 0, 1.f);

  gemm_bt<1><<<dim3(E3_ / 128, M_ / 128), 256, 0, stream>>>(xb, winb, b_in, qkb, vTb, M_, E3_, E_);
  attn_causal<<<dim3(1024), 256, 0, stream>>>(qkb, vTb, ctxb);
  gemm_bt<0><<<dim3(E_ / 128, M_ / 128), 256, 0, stream>>>(ctxb, woutb, b_out, ao, nullptr, M_, E_, E_);
  resid_ln<<<dim3(M_), 256, 0, stream>>>(x, ao, gamma, beta, out);
}

// Round 6
// 213.116 us; speedup vs baseline: 1.1002x; 1.1002x over previous
//
#include <hip/hip_runtime.h>
#include <hip/hip_bf16.h>
#include <stdint.h>

// Problem constants
#define B_   4
#define S_   2048
#define E_   1024
#define H_   16
#define D_   64
#define M_   (B_ * S_)     // 8192 rows
#define E3_  (3 * E_)      // 3072

#define QSCALE 0.18033688011112042f  // 0.125 * log2(e)

typedef __bf16 bf16_t;
typedef bf16_t bf16x8 __attribute__((ext_vector_type(8)));
typedef float  f32x4  __attribute__((ext_vector_type(4)));
typedef float  f32x16 __attribute__((ext_vector_type(16)));

__device__ __forceinline__ ushort f2bf(float f) {
  union { float f; uint32_t u; } v; v.f = f;
  uint32_t r = v.u + 0x7fffu + ((v.u >> 16) & 1u);
  return (ushort)(r >> 16);
}

__device__ __forceinline__ unsigned cvtpk(float lo, float hi_) {
  unsigned d;
  asm("v_cvt_pk_bf16_f32 %0, %1, %2" : "=v"(d) : "v"(lo), "v"(hi_));
  return d;
}

__device__ __forceinline__ void gload_lds16(const void* g, void* l) {
  __builtin_amdgcn_global_load_lds((const __attribute__((address_space(1))) void*)g,
                                   (__attribute__((address_space(3))) void*)l,
                                   16, 0, 0);
}

// ---------------------------------------------------------------- cvt f32->bf16 (optional row-scale)
__global__ __launch_bounds__(256) void cvt_f32_bf16(const float* __restrict__ in,
                                                    ushort* __restrict__ out, int n4,
                                                    int scale_row4, float scale) {
  int i = blockIdx.x * blockDim.x + threadIdx.x;
  if (i < n4) {
    float4 v = reinterpret_cast<const float4*>(in)[i];
    if (i < scale_row4) { v.x *= scale; v.y *= scale; v.z *= scale; v.w *= scale; }
    ushort4 o;
    o.x = f2bf(v.x); o.y = f2bf(v.y); o.z = f2bf(v.z); o.w = f2bf(v.w);
    reinterpret_cast<ushort4*>(out)[i] = o;
  }
}

// ---------------------------------------------------------------- GEMM: C = A @ Bt^T + bias
// MODE 0: f32 out [Mdim][Ndim]. MODE 1: qkv split: cols<2048 -> bf16 qk[row][2048],
//         cols>=2048 -> vT[(b*1024 + col-2048)][2048] packed along s; q-bias scaled.
// XCD-aware bijective block swizzle (T1): nwg must be divisible by 8 (1536 / 512 here).
template <int MODE>
__global__ __launch_bounds__(256) void gemm_bt(const ushort* __restrict__ A,
                                               const ushort* __restrict__ Bt,
                                               const float* __restrict__ bias,
                                               void* __restrict__ out0,
                                               ushort* __restrict__ vTout,
                                               int Mdim, int Ndim, int K) {
  __shared__ __align__(16) ushort As[128 * 32];
  __shared__ __align__(16) ushort Bs[128 * 32];

  const int tid  = threadIdx.x;
  const int lane = tid & 63, wid = tid >> 6;
  const int wr = wid >> 1, wc = wid & 1;

  const int nx = gridDim.x;
  const int nwg = nx * gridDim.y;
  const int b0 = blockIdx.y * nx + blockIdx.x;
  const int nb = (b0 & 7) * (nwg >> 3) + (b0 >> 3);
  const int bm = (nb / nx) * 128, bn = (nb % nx) * 128;

  const int lrow = lane & 15, lk8 = (lane >> 4) * 8, lg4 = (lane >> 4) * 4;
  const int srow = tid >> 2;
  const int skk  = (tid & 3) * 8;

  f32x4 acc[4][4] = {};

  for (int k0 = 0; k0 < K; k0 += 32) {
#pragma unroll
    for (int j = 0; j < 2; ++j) {
      const ushort* ga = A  + (size_t)(bm + j * 64 + srow) * K + k0 + skk;
      const ushort* gb = Bt + (size_t)(bn + j * 64 + srow) * K + k0 + skk;
      gload_lds16(ga, (void*)&As[(j * 256 + wid * 64) * 8]);
      gload_lds16(gb, (void*)&Bs[(j * 256 + wid * 64) * 8]);
    }
    __syncthreads();

    bf16x8 af[4], bfv[4];
#pragma unroll
    for (int rb = 0; rb < 4; ++rb)
      af[rb] = *reinterpret_cast<const bf16x8*>(&As[(wr * 64 + rb * 16 + lrow) * 32 + lk8]);
#pragma unroll
    for (int cb = 0; cb < 4; ++cb)
      bfv[cb] = *reinterpret_cast<const bf16x8*>(&Bs[(wc * 64 + cb * 16 + lrow) * 32 + lk8]);
#pragma unroll
    for (int rb = 0; rb < 4; ++rb)
#pragma unroll
      for (int cb = 0; cb < 4; ++cb)
        acc[rb][cb] = __builtin_amdgcn_mfma_f32_16x16x32_bf16(af[rb], bfv[cb], acc[rb][cb], 0, 0, 0);
    __syncthreads();
  }

#pragma unroll
  for (int rb = 0; rb < 4; ++rb) {
#pragma unroll
    for (int cb = 0; cb < 4; ++cb) {
      const int col = bn + wc * 64 + cb * 16 + lrow;
      float bv = bias[col];
      if (MODE == 1 && col < 1024) bv *= QSCALE;
      const int row0 = bm + wr * 64 + rb * 16 + lg4;
      if (MODE == 0) {
#pragma unroll
        for (int r = 0; r < 4; ++r)
          ((float*)out0)[(size_t)(row0 + r) * Ndim + col] = acc[rb][cb][r] + bv;
      } else {
        if (col < 2048) {
#pragma unroll
          for (int r = 0; r < 4; ++r)
            ((ushort*)out0)[(size_t)(row0 + r) * 2048 + col] = f2bf(acc[rb][cb][r] + bv);
        } else {
          ushort4 vv;
          vv.x = f2bf(acc[rb][cb][0] + bv);
          vv.y = f2bf(acc[rb][cb][1] + bv);
          vv.z = f2bf(acc[rb][cb][2] + bv);
          vv.w = f2bf(acc[rb][cb][3] + bv);
          const size_t vidx = ((size_t)((row0 >> 11) * 1024 + (col - 2048))) * 2048 + (row0 & 2047);
          *reinterpret_cast<ushort4*>(&vTout[vidx]) = vv;
        }
      }
    }
  }
}

// ---------------------------------------------------------------- causal flash attention
// 8 waves x 32 q-rows = 256 q/block (R4 structure). Swapped QK^T: lane owns q = lane&31.
// qk: [M_][2048] bf16 (q | k). vT: [bh*64+d][2048] bf16 (s-contiguous). ctx: [M_][E_] bf16.
__global__ __launch_bounds__(512) void attn_causal(const ushort* __restrict__ qk,
                                                   const ushort* __restrict__ vT,
                                                   ushort* __restrict__ ctx) {
  __shared__ __align__(16) char lds[2][16384];  // [buf][ K 8KB | Vt 8KB ], XOR-swizzled rows

  const int tid = threadIdx.x;
  const int w = tid >> 6, lane = tid & 63;
  const int l31 = lane & 31, hi = lane >> 5;

  const int bid = blockIdx.x;
  const int bh = (bid & 7) * 8 + ((bid >> 3) & 7);  // 8 heads per XCD round
  const int g6 = bid >> 6;
  const int qb = (g6 < 4) ? (7 - g6) : (g6 - 4);    // pair (7,0),(6,1),(5,2),(4,3) per CU
  const int b = bh >> 4, h = bh & 15;
  const int qbase = qb * 256;
  const int tmax = 4 * qb + 3;
  const int qw = qbase + w * 32;
  const int q_g = qw + l31;
  const int my_tmax = (qw + 31) >> 6;

  // Q fragments (scale pre-folded into W_in q-rows)
  const ushort* qrow = qk + (size_t)(b * S_ + q_g) * 2048 + h * 64;
  bf16x8 qf[4];
#pragma unroll
  for (int st = 0; st < 4; ++st)
    qf[st] = *reinterpret_cast<const bf16x8*>(qrow + st * 16 + hi * 8);

  // staging: 512 threads x 16B = one 8KB tile each for K and Vt
  const int srow = tid >> 3;
  const int swz  = ((tid & 7) * 16) ^ ((srow & 7) << 4);
  const char* kbase = (const char*)qk + ((size_t)(b * S_ + srow) * 2048 + 1024 + h * 64) * 2 + swz;
  const char* vbase = (const char*)vT + ((size_t)(bh * 64 + srow) * 2048) * 2 + swz;

  f32x16 Ot0 = {}, Ot1 = {};
  float m_r = -__builtin_inff(), l_r = 0.f;

  const int kswz = ((l31 & 7) << 4);

#define STAGE(T, BUFI)                                                              \
  do {                                                                              \
    gload_lds16(kbase + (size_t)(T) * (64 * 2048 * 2), &lds[BUFI][w * 1024]);       \
    gload_lds16(vbase + (size_t)(T) * 128,             &lds[BUFI][8192 + w * 1024]);\
  } while (0)

  STAGE(0, 0);
  for (int t = 0; t <= tmax; ++t) {
    const int bufi = t & 1;
    if (t < tmax) {
      STAGE(t + 1, bufi ^ 1);
      asm volatile("s_waitcnt vmcnt(2)" ::: "memory");
    } else {
      asm volatile("s_waitcnt vmcnt(0)" ::: "memory");
    }
    __builtin_amdgcn_s_barrier();
    __builtin_amdgcn_sched_barrier(0);

    if (t <= my_tmax) {
      const char* Kt = &lds[bufi][0];
      const char* Vp = &lds[bufi][8192];

      // ---- S^T = K @ Q^T : lane owns column q = l31 ----
      f32x16 T0 = {}, T1 = {};
#pragma unroll
      for (int st = 0; st < 4; ++st) {
        const int cb = (st * 32 + hi * 16) ^ kswz;
        bf16x8 k0 = *(const bf16x8*)(Kt + l31 * 128 + cb);
        bf16x8 k1 = *(const bf16x8*)(Kt + (32 + l31) * 128 + cb);
        T0 = __builtin_amdgcn_mfma_f32_32x32x16_bf16(k0, qf[st], T0, 0, 0, 0);
        T1 = __builtin_amdgcn_mfma_f32_32x32x16_bf16(k1, qf[st], T1, 0, 0, 0);
      }

      // ---- mask + online softmax (lane-local; defer-max THR=8 in exp2 domain; max3 chain) ----
      float p[32];
      const bool needmask = (t * 64 + 63) > qw;
      const int kvb = t * 64 + 4 * hi;
#pragma unroll
      for (int g = 0; g < 4; ++g) {
#pragma unroll
        for (int j = 0; j < 4; ++j) {
          float v0 = T0[4 * g + j], v1 = T1[4 * g + j];
          if (needmask) {
            const int kv0 = kvb + 8 * g + j;
            v0 = (kv0      <= q_g) ? v0 : -__builtin_inff();
            v1 = (kv0 + 32 <= q_g) ? v1 : -__builtin_inff();
          }
          p[4 * g + j] = v0;
          p[16 + 4 * g + j] = v1;
        }
      }
      float pmax = p[0];
#pragma unroll
      for (int i = 1; i < 31; i += 2) pmax = fmaxf(fmaxf(pmax, p[i]), p[i + 1]);  // v_max3
      pmax = fmaxf(pmax, p[31]);
      pmax = fmaxf(pmax, __shfl_xor(pmax, 32));

      if (!__all(pmax - m_r <= 8.f)) {
        const float mn = fmaxf(m_r, pmax);
        const float sc = exp2f(m_r - mn);
        m_r = mn;
        l_r *= sc;
#pragma unroll
        for (int i = 0; i < 16; ++i) { Ot0[i] *= sc; Ot1[i] *= sc; }
      }
      float sum = 0.f;
#pragma unroll
      for (int i = 0; i < 32; ++i) { p[i] = exp2f(p[i] - m_r); sum += p[i]; }
      sum += __shfl_xor(sum, 32);
      l_r += sum;

      // ---- P -> bf16 B-fragments via shfl_xor(32) half-exchange; PV swapped: O^T col = q ----
#pragma unroll
      for (int ks = 0; ks < 4; ++ks) {
        const unsigned a = cvtpk(p[8 * ks + 0], p[8 * ks + 1]);
        const unsigned bq = cvtpk(p[8 * ks + 2], p[8 * ks + 3]);
        const unsigned c = cvtpk(p[8 * ks + 4], p[8 * ks + 5]);
        const unsigned d = cvtpk(p[8 * ks + 6], p[8 * ks + 7]);
        const unsigned x = hi ? a : c;
        const unsigned y = hi ? bq : d;
        const unsigned xp = (unsigned)__shfl_xor((int)x, 32);
        const unsigned yp = (unsigned)__shfl_xor((int)y, 32);
        union { unsigned u[4]; bf16x8 v; } pa;
        pa.u[0] = hi ? xp : a;   // k-elems 0,1
        pa.u[1] = hi ? yp : bq;  // k-elems 2,3
        pa.u[2] = hi ? c : xp;   // k-elems 4,5
        pa.u[3] = hi ? d : yp;   // k-elems 6,7
        const int cb = (ks * 32 + hi * 16) ^ kswz;
        bf16x8 v0 = *(const bf16x8*)(Vp + l31 * 128 + cb);
        bf16x8 v1 = *(const bf16x8*)(Vp + (32 + l31) * 128 + cb);
        Ot0 = __builtin_amdgcn_mfma_f32_32x32x16_bf16(v0, pa.v, Ot0, 0, 0, 0);
        Ot1 = __builtin_amdgcn_mfma_f32_32x32x16_bf16(v1, pa.v, Ot1, 0, 0, 0);
      }
    }
    __builtin_amdgcn_s_barrier();
    __builtin_amdgcn_sched_barrier(0);
  }

  // ---- epilogue: ctx[q][d] = O^T[d][q] / l ----
  const float inv = 1.0f / l_r;
  ushort* crow = ctx + (size_t)(b * S_ + q_g) * 1024 + h * 64;
#pragma unroll
  for (int g = 0; g < 4; ++g) {
#pragma unroll
    for (int jp = 0; jp < 2; ++jp) {
      const int d0 = 2 * jp + 8 * g + 4 * hi;
      const int r = 4 * g + 2 * jp;
      *(unsigned*)(crow + d0)      = cvtpk(Ot0[r] * inv, Ot0[r + 1] * inv);
      *(unsigned*)(crow + 32 + d0) = cvtpk(Ot1[r] * inv, Ot1[r + 1] * inv);
    }
  }
#undef STAGE
}

// ---------------------------------------------------------------- residual + LayerNorm
__global__ __launch_bounds__(256) void resid_ln(const float* __restrict__ x,
                                                const float* __restrict__ ao,
                                                const float* __restrict__ gamma,
                                                const float* __restrict__ beta,
                                                float* __restrict__ out) {
  const int row = blockIdx.x;
  const int tid = threadIdx.x;
  const size_t base = (size_t)row * E_;

  float4 xv = reinterpret_cast<const float4*>(x + base)[tid];
  float4 av = reinterpret_cast<const float4*>(ao + base)[tid];
  const float v0 = xv.x + av.x, v1 = xv.y + av.y, v2 = xv.z + av.z, v3 = xv.w + av.w;
  float s  = v0 + v1 + v2 + v3;
  float s2 = v0 * v0 + v1 * v1 + v2 * v2 + v3 * v3;
#pragma unroll
  for (int off = 32; off >= 1; off >>= 1) {
    s  += __shfl_xor(s, off);
    s2 += __shfl_xor(s2, off);
  }
  __shared__ float red[8];
  const int wid = tid >> 6, lane = tid & 63;
  if (lane == 0) { red[wid] = s; red[4 + wid] = s2; }
  __syncthreads();
  s  = red[0] + red[1] + red[2] + red[3];
  s2 = red[4] + red[5] + red[6] + red[7];
  const float mu  = s * (1.f / E_);
  const float var = s2 * (1.f / E_) - mu * mu;
  const float rsd = rsqrtf(var + 1e-5f);

  float4 gv = reinterpret_cast<const float4*>(gamma)[tid];
  float4 bv = reinterpret_cast<const float4*>(beta)[tid];
  float4 ov;
  ov.x = (v0 - mu) * rsd * gv.x + bv.x;
  ov.y = (v1 - mu) * rsd * gv.y + bv.y;
  ov.z = (v2 - mu) * rsd * gv.z + bv.z;
  ov.w = (v3 - mu) * rsd * gv.w + bv.w;
  reinterpret_cast<float4*>(out + base)[tid] = ov;
}

// ---------------------------------------------------------------- launch
extern "C" void kernel_launch(void* const* d_in, const int* in_sizes, int n_in,
                              void* d_out, int out_size, void* d_ws, size_t ws_size,
                              hipStream_t stream) {
  (void)in_sizes; (void)n_in; (void)out_size; (void)ws_size;
  const float* x     = (const float*)d_in[0];
  const float* w_in  = (const float*)d_in[1];
  const float* b_in  = (const float*)d_in[2];
  const float* w_out = (const float*)d_in[3];
  const float* b_out = (const float*)d_in[4];
  const float* gamma = (const float*)d_in[5];
  const float* beta  = (const float*)d_in[6];
  float* out = (float*)d_out;

  char* ws = (char*)d_ws;
  ushort* xb    = (ushort*)(ws);                          // 16 MB
  ushort* winb  = (ushort*)(ws + 16777216);               // 6 MB
  ushort* woutb = (ushort*)(ws + 23068672);               // 2 MB
  ushort* qkb   = (ushort*)(ws + 25165824);               // 32 MB  [8192][2048]
  ushort* vTb   = (ushort*)(ws + 58720256);               // 16 MB  [4096][2048]
  ushort* ctxb  = (ushort*)(ws + 75497472);               // 16 MB
  float*  ao    = (float*)(ws + 92274688);                // 32 MB  -> total 120 MB

  cvt_f32_bf16<<<dim3((M_ * E_) / 4 / 256), 256, 0, stream>>>(x, xb, (M_ * E_) / 4, 0, 1.f);
  cvt_f32_bf16<<<dim3((E3_ * E_) / 4 / 256), 256, 0, stream>>>(w_in, winb, (E3_ * E_) / 4,
                                                               (E_ * E_) / 4, QSCALE);
  cvt_f32_bf16<<<dim3((E_ * E_) / 4 / 256), 256, 0, stream>>>(w_out, woutb, (E_ * E_) / 4, 0, 1.f);

  gemm_bt<1><<<dim3(E3_ / 128, M_ / 128), 256, 0, stream>>>(xb, winb, b_in, qkb, vTb, M_, E3_, E_);
  attn_causal<<<dim3(512), 512, 0, stream>>>(qkb, vTb, ctxb);
  gemm_bt<0><<<dim3(E_ / 128, M_ / 128), 256, 0, stream>>>(ctxb, woutb, b_out, ao, nullptr, M_, E_, E_);
  resid_ln<<<dim3(M_), 256, 0, stream>>>(x, ao, gamma, beta, out);
}